// Round 1
// baseline (215.240 us; speedup 1.0000x reference)
//
#include <hip/hip_runtime.h>

typedef unsigned int uint_t;
typedef unsigned short ushort_t;

constexpr int MAXDEG = 64;   // deg ~ Poisson(16): P(deg >= 64) ~ 3e-22 per node — guarded anyway
constexpr int CSTRIDE = 16;  // cursor/deg padded to one counter per 64B cacheline:
                             // 800K device-scope returning atomics to a dense int[50000] put
                             // ~256 RMWs on each 64B line at the cross-XCD coherence point;
                             // padding cuts per-line serialization to ~16 (the node's own degree).

// ---------------- bf16 helpers (RNE) ----------------
static __device__ __forceinline__ uint_t f2bf_bits(float f) {
  uint_t u = __builtin_bit_cast(uint_t, f);
  return (u + 0x7fffu + ((u >> 16) & 1u)) >> 16;
}
static __device__ __forceinline__ uint_t pack_bf2(float lo, float hi) {
  return f2bf_bits(lo) | (f2bf_bits(hi) << 16);
}
static __device__ __forceinline__ float bf_lo(uint_t u) {
  return __builtin_bit_cast(float, u << 16);
}
static __device__ __forceinline__ float bf_hi(uint_t u) {
  return __builtin_bit_cast(float, u & 0xffff0000u);
}

static inline size_t align256(size_t x) { return (x + 255) & ~(size_t)255; }

// ---------------- fused GEMM1 + CSR fill ----------------
// Prologue (per thread, grid-strided): slot = atomicAdd(cursor[dst*CSTRIDE]); edge[dst*64+slot] = src.
// Stores are fire-and-forget; their drain overlaps the GEMM main loop.
// GEMM: outG(bf16) = X @ W1   (raw — dinv[src] is folded in at aggregation time).
template<typename IdxT>
__global__ __launch_bounds__(256) void gemm1_fill_kernel(
    const float* __restrict__ X, const float* __restrict__ W1,
    uint_t* __restrict__ outG, int Nrows,
    const int* __restrict__ src, const int* __restrict__ dst,
    int* __restrict__ cursor, IdxT* __restrict__ edge, int E) {
  constexpr int BK = 64;
  __shared__ float wlds[BK][128];
  __shared__ float xT[BK][68];

  const int tid = threadIdx.x;

  // ---- fill prologue: scatter edges; writes drain under the GEMM below ----
  {
    const int gtid = blockIdx.x * 256 + tid;
    const int T = gridDim.x * 256;
    for (int e = gtid; e < E; e += T) {
      int d = dst[e];
      int s = src[e];
      int slot = atomicAdd(&cursor[(size_t)d * CSTRIDE], 1);
      if (slot < MAXDEG) edge[(size_t)d * MAXDEG + slot] = (IdxT)s;
    }
  }

  const int cg = tid & 31;
  const int rl = tid >> 5;
  const int rowbase = blockIdx.x * 64;

  float acc[8][4];
#pragma unroll
  for (int i = 0; i < 8; ++i)
#pragma unroll
    for (int j = 0; j < 4; ++j) acc[i][j] = 0.f;

  for (int k0 = 0; k0 < 128; k0 += BK) {
    __syncthreads();
#pragma unroll
    for (int i = 0; i < 8; ++i) {
      int f = tid + i * 256;
      int kk = f >> 5, cc = f & 31;
      float4 v = ((const float4*)W1)[(size_t)(k0 + kk) * 32 + cc];
      *(float4*)&wlds[kk][cc * 4] = v;
    }
    {
      int r = tid >> 2;
      int rg = rowbase + r;
      int rs = (rg < Nrows) ? rg : (Nrows - 1);
      const float4* xrow = (const float4*)(X + (size_t)rs * 128);
      bool valid = (rg < Nrows);
#pragma unroll
      for (int p = 0; p < 4; ++p) {
        int kf4 = (tid & 3) + p * 4;
        float4 v = xrow[(k0 >> 2) + kf4];
        if (!valid) v = make_float4(0.f, 0.f, 0.f, 0.f);
        int ke = kf4 * 4;
        xT[ke + 0][r] = v.x;
        xT[ke + 1][r] = v.y;
        xT[ke + 2][r] = v.z;
        xT[ke + 3][r] = v.w;
      }
    }
    __syncthreads();
#pragma unroll 8
    for (int kk = 0; kk < BK; ++kk) {
      float4 xa = *(const float4*)&xT[kk][rl * 8];
      float4 xb = *(const float4*)&xT[kk][rl * 8 + 4];
      float4 wv = *(const float4*)&wlds[kk][cg * 4];
      float xr[8] = {xa.x, xa.y, xa.z, xa.w, xb.x, xb.y, xb.z, xb.w};
      float wc[4] = {wv.x, wv.y, wv.z, wv.w};
#pragma unroll
      for (int i = 0; i < 8; ++i)
#pragma unroll
        for (int j = 0; j < 4; ++j)
          acc[i][j] = fmaf(xr[i], wc[j], acc[i][j]);
    }
  }
#pragma unroll
  for (int i = 0; i < 8; ++i) {
    int r = rowbase + rl * 8 + i;
    if (r >= Nrows) continue;
    uint2 o;
    o.x = pack_bf2(acc[i][0], acc[i][1]);
    o.y = pack_bf2(acc[i][2], acc[i][3]);
    ((uint2*)outG)[(size_t)r * 32 + cg] = o;
  }
}

// ---------------- GEMM2: mean/std(fp32) = Xbf @ [W3|W4] + [b3|b4] ----------------
__global__ __launch_bounds__(256) void gemm2_kernel(
    const uint_t* __restrict__ Xbf, const float* __restrict__ W3, const float* __restrict__ W4,
    const float* __restrict__ b3, const float* __restrict__ b4,
    float* __restrict__ outM, float* __restrict__ outS, int Nrows) {
  constexpr int BK = 64;
  __shared__ float wlds[BK][128];
  __shared__ float xT[BK][68];

  const int tid = threadIdx.x;
  const int cg = tid & 31;
  const int rl = tid >> 5;
  const int rowbase = blockIdx.x * 64;

  float acc[8][4];
#pragma unroll
  for (int i = 0; i < 8; ++i)
#pragma unroll
    for (int j = 0; j < 4; ++j) acc[i][j] = 0.f;

  for (int k0 = 0; k0 < 128; k0 += BK) {
    __syncthreads();
#pragma unroll
    for (int i = 0; i < 8; ++i) {
      int f = tid + i * 256;
      int kk = f >> 5, cc = f & 31;
      float4 v = (cc < 16) ? ((const float4*)W3)[(size_t)(k0 + kk) * 16 + cc]
                           : ((const float4*)W4)[(size_t)(k0 + kk) * 16 + (cc - 16)];
      *(float4*)&wlds[kk][cc * 4] = v;
    }
    {
      int r = tid >> 2;
      int rg = rowbase + r;
      int rs = (rg < Nrows) ? rg : (Nrows - 1);
      const uint4* xrow = (const uint4*)(Xbf + (size_t)rs * 64);
      bool valid = (rg < Nrows);
#pragma unroll
      for (int p = 0; p < 2; ++p) {
        int kf8 = (tid & 3) + p * 4;
        uint4 v = xrow[(k0 >> 3) + kf8];
        if (!valid) v = make_uint4(0, 0, 0, 0);
        int ke = kf8 * 8;
        xT[ke + 0][r] = bf_lo(v.x); xT[ke + 1][r] = bf_hi(v.x);
        xT[ke + 2][r] = bf_lo(v.y); xT[ke + 3][r] = bf_hi(v.y);
        xT[ke + 4][r] = bf_lo(v.z); xT[ke + 5][r] = bf_hi(v.z);
        xT[ke + 6][r] = bf_lo(v.w); xT[ke + 7][r] = bf_hi(v.w);
      }
    }
    __syncthreads();
#pragma unroll 8
    for (int kk = 0; kk < BK; ++kk) {
      float4 xa = *(const float4*)&xT[kk][rl * 8];
      float4 xb = *(const float4*)&xT[kk][rl * 8 + 4];
      float4 wv = *(const float4*)&wlds[kk][cg * 4];
      float xr[8] = {xa.x, xa.y, xa.z, xa.w, xb.x, xb.y, xb.z, xb.w};
      float wc[4] = {wv.x, wv.y, wv.z, wv.w};
#pragma unroll
      for (int i = 0; i < 8; ++i)
#pragma unroll
        for (int j = 0; j < 4; ++j)
          acc[i][j] = fmaf(xr[i], wc[j], acc[i][j]);
    }
  }
  float4 bv = (cg < 16) ? ((const float4*)b3)[cg] : ((const float4*)b4)[cg - 16];
#pragma unroll
  for (int i = 0; i < 8; ++i) {
    int r = rowbase + rl * 8 + i;
    if (r >= Nrows) continue;
    float4 o;
    o.x = acc[i][0] + bv.x; o.y = acc[i][1] + bv.y;
    o.z = acc[i][2] + bv.z; o.w = acc[i][3] + bv.w;
    if (cg < 16) ((float4*)outM)[(size_t)r * 16 + cg] = o;
    else         ((float4*)outS)[(size_t)r * 16 + (cg - 16)] = o;
  }
}

// ---------------- gather aggregation (bf16 in/out, fp32 accum) ----------------
// dinv computed on the fly from deg (= cursor, stride CSTRIDE). One wave per node.
// SRCDV: weight each gathered row by dinv[s] (layer-1 agg, where g = raw xW1).
// EPI 1: out = sc * relu(sc * sum + b1)     (pre-scaled hidden for next layer)
// EPI 2: out = sc * sum
template<int EPI, bool SRCDV, typename IdxT>
__global__ __launch_bounds__(256) void aggregate_kernel(
    const uint_t* __restrict__ g, const int* __restrict__ deg,
    const IdxT* __restrict__ edge, const float* __restrict__ b1,
    uint_t* __restrict__ out, int Nn) {
  int wave = threadIdx.x >> 6;
  int lane = threadIdx.x & 63;
  int n = blockIdx.x * 4 + wave;
  if (n >= Nn) return;
  int dn = deg[(size_t)n * CSTRIDE];
  int cnt = (dn > MAXDEG) ? MAXDEG : dn;
  float sc = rsqrtf((float)(dn + 1));
  // whole edge row in one coalesced wave-load (64 x 2B = 128B for ushort)
  int myidx = (lane < cnt) ? (int)edge[(size_t)n * MAXDEG + lane] : 0;
  float mydv = 0.f;
  if (SRCDV) mydv = (lane < cnt) ? rsqrtf((float)(deg[(size_t)myidx * CSTRIDE] + 1)) : 0.f;
  uint_t su = g[(size_t)n * 64 + lane];
  float selfw = SRCDV ? sc : 1.f;
  float a0x = selfw * bf_lo(su), a0y = selfw * bf_hi(su);
  float a1x = 0.f, a1y = 0.f;
  float a2x = 0.f, a2y = 0.f;
  float a3x = 0.f, a3y = 0.f;
  int i = 0;
  for (; i + 3 < cnt; i += 4) {
    int s0 = __shfl(myidx, i);
    int s1 = __shfl(myidx, i + 1);
    int s2 = __shfl(myidx, i + 2);
    int s3 = __shfl(myidx, i + 3);
    uint_t u0 = g[(size_t)s0 * 64 + lane];
    uint_t u1 = g[(size_t)s1 * 64 + lane];
    uint_t u2 = g[(size_t)s2 * 64 + lane];
    uint_t u3 = g[(size_t)s3 * 64 + lane];
    if (SRCDV) {
      float d0 = __shfl(mydv, i);
      float d1 = __shfl(mydv, i + 1);
      float d2 = __shfl(mydv, i + 2);
      float d3 = __shfl(mydv, i + 3);
      a0x = fmaf(d0, bf_lo(u0), a0x); a0y = fmaf(d0, bf_hi(u0), a0y);
      a1x = fmaf(d1, bf_lo(u1), a1x); a1y = fmaf(d1, bf_hi(u1), a1y);
      a2x = fmaf(d2, bf_lo(u2), a2x); a2y = fmaf(d2, bf_hi(u2), a2y);
      a3x = fmaf(d3, bf_lo(u3), a3x); a3y = fmaf(d3, bf_hi(u3), a3y);
    } else {
      a0x += bf_lo(u0); a0y += bf_hi(u0);
      a1x += bf_lo(u1); a1y += bf_hi(u1);
      a2x += bf_lo(u2); a2y += bf_hi(u2);
      a3x += bf_lo(u3); a3y += bf_hi(u3);
    }
  }
  for (; i < cnt; ++i) {
    int s0 = __shfl(myidx, i);
    uint_t u0 = g[(size_t)s0 * 64 + lane];
    if (SRCDV) {
      float d0 = __shfl(mydv, i);
      a0x = fmaf(d0, bf_lo(u0), a0x); a0y = fmaf(d0, bf_hi(u0), a0y);
    } else {
      a0x += bf_lo(u0); a0y += bf_hi(u0);
    }
  }
  float ox = (a0x + a1x) + (a2x + a3x);
  float oy = (a0y + a1y) + (a2y + a3y);
  if (EPI == 1) {
    float2 b = ((const float2*)b1)[lane];
    ox = fmaxf(fmaf(sc, ox, b.x), 0.f) * sc;
    oy = fmaxf(fmaf(sc, oy, b.y), 0.f) * sc;
  } else {
    ox *= sc; oy *= sc;
  }
  out[(size_t)n * 64 + lane] = pack_bf2(ox, oy);
}

// ---------------- launch ----------------
extern "C" void kernel_launch(void* const* d_in, const int* in_sizes, int n_in,
                              void* d_out, int out_size, void* d_ws, size_t ws_size,
                              hipStream_t stream) {
  const float* x  = (const float*)d_in[0];
  const int*   ei = (const int*)d_in[1];
  const float* W1 = (const float*)d_in[2];
  const float* b1 = (const float*)d_in[3];
  const float* W3 = (const float*)d_in[4];
  const float* b3 = (const float*)d_in[5];
  const float* W4 = (const float*)d_in[6];
  const float* b4 = (const float*)d_in[7];

  const int N = in_sizes[0] / 128;
  const int E = in_sizes[1] / 2;
  const int* src = ei;
  const int* dst = ei + E;

  char* w = (char*)d_ws;
  size_t off = 0;
  auto carve = [&](size_t bytes) { void* p = w + off; off = align256(off + bytes); return p; };
  int*    cursor = (int*)carve((size_t)N * CSTRIDE * sizeof(int));   // becomes deg after fill (64B-padded)
  void*   edge   = carve((size_t)N * MAXDEG * sizeof(int));          // sized for int fallback
  uint_t* bufG   = (uint_t*)carve((size_t)N * 64 * sizeof(uint_t));  // [N,128] bf16
  uint_t* bufH   = (uint_t*)carve((size_t)N * 64 * sizeof(uint_t));

  float* out_mean = (float*)d_out;
  float* out_std  = out_mean + (size_t)N * 64;

  hipMemsetAsync(cursor, 0, (size_t)N * CSTRIDE * sizeof(int), stream);

  const int gblocks = (N + 63) / 64;
  const int ablocks = (N + 3) / 4;

  if (N <= 65535) {
    ushort_t* es = (ushort_t*)edge;
    gemm1_fill_kernel<ushort_t><<<gblocks, 256, 0, stream>>>(
        x, W1, bufG, N, src, dst, cursor, es, E);
    aggregate_kernel<1, true,  ushort_t><<<ablocks, 256, 0, stream>>>(bufG, cursor, es, b1, bufH, N);
    aggregate_kernel<2, false, ushort_t><<<ablocks, 256, 0, stream>>>(bufH, cursor, es, nullptr, bufG, N);
  } else {
    int* es = (int*)edge;
    gemm1_fill_kernel<int><<<gblocks, 256, 0, stream>>>(
        x, W1, bufG, N, src, dst, cursor, es, E);
    aggregate_kernel<1, true,  int><<<ablocks, 256, 0, stream>>>(bufG, cursor, es, b1, bufH, N);
    aggregate_kernel<2, false, int><<<ablocks, 256, 0, stream>>>(bufH, cursor, es, nullptr, bufG, N);
  }
  gemm2_kernel<<<gblocks, 256, 0, stream>>>(bufG, W3, W4, b3, b4, out_mean, out_std, N);
}

// Round 2
// 182.960 us; speedup vs baseline: 1.1764x; 1.1764x over previous
//
#include <hip/hip_runtime.h>

typedef unsigned int uint_t;
typedef unsigned short ushort_t;

constexpr int MAXDEG = 64;   // deg ~ Poisson(16): P(deg >= 64) ~ 3e-22 per node — guarded anyway
// NOTE (R1 post-mortem): padding cursor to 64B/counter (CSTRIDE=16) REGRESSED 102->114us.
// Dense cursor is better: TCC-side atomic units handle same-line ops fine; padding only
// bloated the footprint. Reverted to dense int[N].

// ---------------- bf16 helpers (RNE) ----------------
static __device__ __forceinline__ uint_t f2bf_bits(float f) {
  uint_t u = __builtin_bit_cast(uint_t, f);
  return (u + 0x7fffu + ((u >> 16) & 1u)) >> 16;
}
static __device__ __forceinline__ uint_t pack_bf2(float lo, float hi) {
  return f2bf_bits(lo) | (f2bf_bits(hi) << 16);
}
static __device__ __forceinline__ float bf_lo(uint_t u) {
  return __builtin_bit_cast(float, u << 16);
}
static __device__ __forceinline__ float bf_hi(uint_t u) {
  return __builtin_bit_cast(float, u & 0xffff0000u);
}

static inline size_t align256(size_t x) { return (x + 255) & ~(size_t)255; }

// ---------------- fused GEMM1 + CSR fill ----------------
// Prologue: batched 3-phase scatter (loads -> 4 independent returning atomics in
// flight -> one wait -> stores). The old grid-stride loop serialized 4 dependent
// atomic round-trips (~1-2K cyc each, memory-side) per wave before the GEMM.
// GEMM: outG(bf16) = X @ W1   (raw — dinv[src] is folded in at aggregation time).
template<typename IdxT>
__global__ __launch_bounds__(256) void gemm1_fill_kernel(
    const float* __restrict__ X, const float* __restrict__ W1,
    uint_t* __restrict__ outG, int Nrows,
    const int* __restrict__ src, const int* __restrict__ dst,
    int* __restrict__ cursor, IdxT* __restrict__ edge, int E) {
  constexpr int BK = 64;
  __shared__ float wlds[BK][128];
  __shared__ float xT[BK][68];

  const int tid = threadIdx.x;

  // ---- fill prologue: pipelined scatter; stores drain under the GEMM below ----
  {
    const int gtid = blockIdx.x * 256 + tid;
    const int T = gridDim.x * 256;
    for (int base = gtid; base < E; base += 4 * T) {
      int d[4], s[4], slot[4];
      bool ok[4];
#pragma unroll
      for (int k = 0; k < 4; ++k) {
        int e = base + k * T;
        ok[k] = (e < E);
        d[k] = ok[k] ? dst[e] : 0;
        s[k] = ok[k] ? src[e] : 0;
      }
#pragma unroll
      for (int k = 0; k < 4; ++k) {
        slot[k] = ok[k] ? atomicAdd(&cursor[d[k]], 1) : MAXDEG;
      }
#pragma unroll
      for (int k = 0; k < 4; ++k) {
        if (slot[k] < MAXDEG) edge[(size_t)d[k] * MAXDEG + slot[k]] = (IdxT)s[k];
      }
    }
  }

  const int cg = tid & 31;
  const int rl = tid >> 5;
  const int rowbase = blockIdx.x * 64;

  float acc[8][4];
#pragma unroll
  for (int i = 0; i < 8; ++i)
#pragma unroll
    for (int j = 0; j < 4; ++j) acc[i][j] = 0.f;

  for (int k0 = 0; k0 < 128; k0 += BK) {
    __syncthreads();
#pragma unroll
    for (int i = 0; i < 8; ++i) {
      int f = tid + i * 256;
      int kk = f >> 5, cc = f & 31;
      float4 v = ((const float4*)W1)[(size_t)(k0 + kk) * 32 + cc];
      *(float4*)&wlds[kk][cc * 4] = v;
    }
    {
      int r = tid >> 2;
      int rg = rowbase + r;
      int rs = (rg < Nrows) ? rg : (Nrows - 1);
      const float4* xrow = (const float4*)(X + (size_t)rs * 128);
      bool valid = (rg < Nrows);
#pragma unroll
      for (int p = 0; p < 4; ++p) {
        int kf4 = (tid & 3) + p * 4;
        float4 v = xrow[(k0 >> 2) + kf4];
        if (!valid) v = make_float4(0.f, 0.f, 0.f, 0.f);
        int ke = kf4 * 4;
        xT[ke + 0][r] = v.x;
        xT[ke + 1][r] = v.y;
        xT[ke + 2][r] = v.z;
        xT[ke + 3][r] = v.w;
      }
    }
    __syncthreads();
#pragma unroll 8
    for (int kk = 0; kk < BK; ++kk) {
      float4 xa = *(const float4*)&xT[kk][rl * 8];
      float4 xb = *(const float4*)&xT[kk][rl * 8 + 4];
      float4 wv = *(const float4*)&wlds[kk][cg * 4];
      float xr[8] = {xa.x, xa.y, xa.z, xa.w, xb.x, xb.y, xb.z, xb.w};
      float wc[4] = {wv.x, wv.y, wv.z, wv.w};
#pragma unroll
      for (int i = 0; i < 8; ++i)
#pragma unroll
        for (int j = 0; j < 4; ++j)
          acc[i][j] = fmaf(xr[i], wc[j], acc[i][j]);
    }
  }
#pragma unroll
  for (int i = 0; i < 8; ++i) {
    int r = rowbase + rl * 8 + i;
    if (r >= Nrows) continue;
    uint2 o;
    o.x = pack_bf2(acc[i][0], acc[i][1]);
    o.y = pack_bf2(acc[i][2], acc[i][3]);
    ((uint2*)outG)[(size_t)r * 32 + cg] = o;
  }
}

// ---------------- GEMM2: mean/std(fp32) = Xbf @ [W3|W4] + [b3|b4] ----------------
__global__ __launch_bounds__(256) void gemm2_kernel(
    const uint_t* __restrict__ Xbf, const float* __restrict__ W3, const float* __restrict__ W4,
    const float* __restrict__ b3, const float* __restrict__ b4,
    float* __restrict__ outM, float* __restrict__ outS, int Nrows) {
  constexpr int BK = 64;
  __shared__ float wlds[BK][128];
  __shared__ float xT[BK][68];

  const int tid = threadIdx.x;
  const int cg = tid & 31;
  const int rl = tid >> 5;
  const int rowbase = blockIdx.x * 64;

  float acc[8][4];
#pragma unroll
  for (int i = 0; i < 8; ++i)
#pragma unroll
    for (int j = 0; j < 4; ++j) acc[i][j] = 0.f;

  for (int k0 = 0; k0 < 128; k0 += BK) {
    __syncthreads();
#pragma unroll
    for (int i = 0; i < 8; ++i) {
      int f = tid + i * 256;
      int kk = f >> 5, cc = f & 31;
      float4 v = (cc < 16) ? ((const float4*)W3)[(size_t)(k0 + kk) * 16 + cc]
                           : ((const float4*)W4)[(size_t)(k0 + kk) * 16 + (cc - 16)];
      *(float4*)&wlds[kk][cc * 4] = v;
    }
    {
      int r = tid >> 2;
      int rg = rowbase + r;
      int rs = (rg < Nrows) ? rg : (Nrows - 1);
      const uint4* xrow = (const uint4*)(Xbf + (size_t)rs * 64);
      bool valid = (rg < Nrows);
#pragma unroll
      for (int p = 0; p < 2; ++p) {
        int kf8 = (tid & 3) + p * 4;
        uint4 v = xrow[(k0 >> 3) + kf8];
        if (!valid) v = make_uint4(0, 0, 0, 0);
        int ke = kf8 * 8;
        xT[ke + 0][r] = bf_lo(v.x); xT[ke + 1][r] = bf_hi(v.x);
        xT[ke + 2][r] = bf_lo(v.y); xT[ke + 3][r] = bf_hi(v.y);
        xT[ke + 4][r] = bf_lo(v.z); xT[ke + 5][r] = bf_hi(v.z);
        xT[ke + 6][r] = bf_lo(v.w); xT[ke + 7][r] = bf_hi(v.w);
      }
    }
    __syncthreads();
#pragma unroll 8
    for (int kk = 0; kk < BK; ++kk) {
      float4 xa = *(const float4*)&xT[kk][rl * 8];
      float4 xb = *(const float4*)&xT[kk][rl * 8 + 4];
      float4 wv = *(const float4*)&wlds[kk][cg * 4];
      float xr[8] = {xa.x, xa.y, xa.z, xa.w, xb.x, xb.y, xb.z, xb.w};
      float wc[4] = {wv.x, wv.y, wv.z, wv.w};
#pragma unroll
      for (int i = 0; i < 8; ++i)
#pragma unroll
        for (int j = 0; j < 4; ++j)
          acc[i][j] = fmaf(xr[i], wc[j], acc[i][j]);
    }
  }
  float4 bv = (cg < 16) ? ((const float4*)b3)[cg] : ((const float4*)b4)[cg - 16];
#pragma unroll
  for (int i = 0; i < 8; ++i) {
    int r = rowbase + rl * 8 + i;
    if (r >= Nrows) continue;
    float4 o;
    o.x = acc[i][0] + bv.x; o.y = acc[i][1] + bv.y;
    o.z = acc[i][2] + bv.z; o.w = acc[i][3] + bv.w;
    if (cg < 16) ((float4*)outM)[(size_t)r * 16 + cg] = o;
    else         ((float4*)outS)[(size_t)r * 16 + (cg - 16)] = o;
  }
}

// ---------------- gather aggregation (bf16 in/out, fp32 accum) ----------------
// dinv computed on the fly from deg (= cursor). One wave per node.
// SRCDV: weight each gathered row by dinv[s] (layer-1 agg, where g = raw xW1).
// EPI 1: out = sc * relu(sc * sum + b1)     (pre-scaled hidden for next layer)
// EPI 2: out = sc * sum
template<int EPI, bool SRCDV, typename IdxT>
__global__ __launch_bounds__(256) void aggregate_kernel(
    const uint_t* __restrict__ g, const int* __restrict__ deg,
    const IdxT* __restrict__ edge, const float* __restrict__ b1,
    uint_t* __restrict__ out, int Nn) {
  int wave = threadIdx.x >> 6;
  int lane = threadIdx.x & 63;
  int n = blockIdx.x * 4 + wave;
  if (n >= Nn) return;
  int dn = deg[n];
  int cnt = (dn > MAXDEG) ? MAXDEG : dn;
  float sc = rsqrtf((float)(dn + 1));
  // whole edge row in one coalesced wave-load (64 x 2B = 128B for ushort)
  int myidx = (lane < cnt) ? (int)edge[(size_t)n * MAXDEG + lane] : 0;
  float mydv = 0.f;
  if (SRCDV) mydv = (lane < cnt) ? rsqrtf((float)(deg[myidx] + 1)) : 0.f;
  uint_t su = g[(size_t)n * 64 + lane];
  float selfw = SRCDV ? sc : 1.f;
  float a0x = selfw * bf_lo(su), a0y = selfw * bf_hi(su);
  float a1x = 0.f, a1y = 0.f;
  float a2x = 0.f, a2y = 0.f;
  float a3x = 0.f, a3y = 0.f;
  int i = 0;
  for (; i + 3 < cnt; i += 4) {
    int s0 = __shfl(myidx, i);
    int s1 = __shfl(myidx, i + 1);
    int s2 = __shfl(myidx, i + 2);
    int s3 = __shfl(myidx, i + 3);
    uint_t u0 = g[(size_t)s0 * 64 + lane];
    uint_t u1 = g[(size_t)s1 * 64 + lane];
    uint_t u2 = g[(size_t)s2 * 64 + lane];
    uint_t u3 = g[(size_t)s3 * 64 + lane];
    if (SRCDV) {
      float d0 = __shfl(mydv, i);
      float d1 = __shfl(mydv, i + 1);
      float d2 = __shfl(mydv, i + 2);
      float d3 = __shfl(mydv, i + 3);
      a0x = fmaf(d0, bf_lo(u0), a0x); a0y = fmaf(d0, bf_hi(u0), a0y);
      a1x = fmaf(d1, bf_lo(u1), a1x); a1y = fmaf(d1, bf_hi(u1), a1y);
      a2x = fmaf(d2, bf_lo(u2), a2x); a2y = fmaf(d2, bf_hi(u2), a2y);
      a3x = fmaf(d3, bf_lo(u3), a3x); a3y = fmaf(d3, bf_hi(u3), a3y);
    } else {
      a0x += bf_lo(u0); a0y += bf_hi(u0);
      a1x += bf_lo(u1); a1y += bf_hi(u1);
      a2x += bf_lo(u2); a2y += bf_hi(u2);
      a3x += bf_lo(u3); a3y += bf_hi(u3);
    }
  }
  for (; i < cnt; ++i) {
    int s0 = __shfl(myidx, i);
    uint_t u0 = g[(size_t)s0 * 64 + lane];
    if (SRCDV) {
      float d0 = __shfl(mydv, i);
      a0x = fmaf(d0, bf_lo(u0), a0x); a0y = fmaf(d0, bf_hi(u0), a0y);
    } else {
      a0x += bf_lo(u0); a0y += bf_hi(u0);
    }
  }
  float ox = (a0x + a1x) + (a2x + a3x);
  float oy = (a0y + a1y) + (a2y + a3y);
  if (EPI == 1) {
    float2 b = ((const float2*)b1)[lane];
    ox = fmaxf(fmaf(sc, ox, b.x), 0.f) * sc;
    oy = fmaxf(fmaf(sc, oy, b.y), 0.f) * sc;
  } else {
    ox *= sc; oy *= sc;
  }
  out[(size_t)n * 64 + lane] = pack_bf2(ox, oy);
}

// ---------------- launch ----------------
extern "C" void kernel_launch(void* const* d_in, const int* in_sizes, int n_in,
                              void* d_out, int out_size, void* d_ws, size_t ws_size,
                              hipStream_t stream) {
  const float* x  = (const float*)d_in[0];
  const int*   ei = (const int*)d_in[1];
  const float* W1 = (const float*)d_in[2];
  const float* b1 = (const float*)d_in[3];
  const float* W3 = (const float*)d_in[4];
  const float* b3 = (const float*)d_in[5];
  const float* W4 = (const float*)d_in[6];
  const float* b4 = (const float*)d_in[7];

  const int N = in_sizes[0] / 128;
  const int E = in_sizes[1] / 2;
  const int* src = ei;
  const int* dst = ei + E;

  char* w = (char*)d_ws;
  size_t off = 0;
  auto carve = [&](size_t bytes) { void* p = w + off; off = align256(off + bytes); return p; };
  int*    cursor = (int*)carve((size_t)N * sizeof(int));             // becomes deg after fill
  void*   edge   = carve((size_t)N * MAXDEG * sizeof(int));          // sized for int fallback
  uint_t* bufG   = (uint_t*)carve((size_t)N * 64 * sizeof(uint_t));  // [N,128] bf16
  uint_t* bufH   = (uint_t*)carve((size_t)N * 64 * sizeof(uint_t));

  float* out_mean = (float*)d_out;
  float* out_std  = out_mean + (size_t)N * 64;

  hipMemsetAsync(cursor, 0, (size_t)N * sizeof(int), stream);

  const int gblocks = (N + 63) / 64;
  const int ablocks = (N + 3) / 4;

  if (N <= 65535) {
    ushort_t* es = (ushort_t*)edge;
    gemm1_fill_kernel<ushort_t><<<gblocks, 256, 0, stream>>>(
        x, W1, bufG, N, src, dst, cursor, es, E);
    aggregate_kernel<1, true,  ushort_t><<<ablocks, 256, 0, stream>>>(bufG, cursor, es, b1, bufH, N);
    aggregate_kernel<2, false, ushort_t><<<ablocks, 256, 0, stream>>>(bufH, cursor, es, nullptr, bufG, N);
  } else {
    int* es = (int*)edge;
    gemm1_fill_kernel<int><<<gblocks, 256, 0, stream>>>(
        x, W1, bufG, N, src, dst, cursor, es, E);
    aggregate_kernel<1, true,  int><<<ablocks, 256, 0, stream>>>(bufG, cursor, es, b1, bufH, N);
    aggregate_kernel<2, false, int><<<ablocks, 256, 0, stream>>>(bufH, cursor, es, nullptr, bufG, N);
  }
  gemm2_kernel<<<gblocks, 256, 0, stream>>>(bufG, W3, W4, b3, b4, out_mean, out_std, N);
}

// Round 3
// 174.933 us; speedup vs baseline: 1.2304x; 1.0459x over previous
//
#include <hip/hip_runtime.h>

typedef unsigned int uint_t;
typedef unsigned short ushort_t;

constexpr int MAXDEG = 64;   // deg ~ Poisson(16): P(deg >= 64) ~ 3e-22 per node — guarded anyway
// R1 post-mortem: cacheline-padding cursor REGRESSED (102->114us) — dense cursor is fine.
// R2 post-mortem: batching 4 atomics 114->73us (atomic latency confirmed). Remaining stall:
//   __syncthreads lowers to s_waitcnt vmcnt(0) before s_barrier, so the atomic returns were
//   drained BEFORE the GEMM. v3: issue staging loads first (vmcnt FIFO => consuming them
//   never waits on the younger atomics), raw s_barrier + manual lgkmcnt, slots consumed in
//   the epilogue. Atomic service queue now drains concurrently with the GEMM.

// ---------------- bf16 helpers (RNE) ----------------
static __device__ __forceinline__ uint_t f2bf_bits(float f) {
  uint_t u = __builtin_bit_cast(uint_t, f);
  return (u + 0x7fffu + ((u >> 16) & 1u)) >> 16;
}
static __device__ __forceinline__ uint_t pack_bf2(float lo, float hi) {
  return f2bf_bits(lo) | (f2bf_bits(hi) << 16);
}
static __device__ __forceinline__ float bf_lo(uint_t u) {
  return __builtin_bit_cast(float, u << 16);
}
static __device__ __forceinline__ float bf_hi(uint_t u) {
  return __builtin_bit_cast(float, u & 0xffff0000u);
}

static inline size_t align256(size_t x) { return (x + 255) & ~(size_t)255; }

static __device__ __forceinline__ void lds_fence_barrier() {
  // LDS-only barrier: ds ops visible across the workgroup WITHOUT draining vmcnt
  // (the whole point: atomic returns stay in flight across the GEMM).
  asm volatile("s_waitcnt lgkmcnt(0)" ::: "memory");
  __builtin_amdgcn_s_barrier();
}

// ---------------- fused GEMM1 + CSR fill (v3: atomic-overlap schedule) ----------------
template<typename IdxT>
__global__ __launch_bounds__(256, 3) void gemm1_fill_kernel(
    const float* __restrict__ X, const float* __restrict__ W1,
    uint_t* __restrict__ outG, int Nrows,
    const int* __restrict__ src, const int* __restrict__ dst,
    int* __restrict__ cursor, IdxT* __restrict__ edge, int E) {
  __shared__ float wlds[64][128];
  __shared__ float xT[64][68];

  const int tid = threadIdx.x;
  const int gtid = blockIdx.x * 256 + tid;
  const int T = gridDim.x * 256;

  // ---- rare remainder (E > 4*T): plain loop, usually zero iterations ----
  for (int e = gtid + 4 * T; e < E; e += T) {
    int d = dst[e], s = src[e];
    int slot = atomicAdd(&cursor[d], 1);
    if (slot < MAXDEG) edge[(size_t)d * MAXDEG + slot] = (IdxT)s;
  }

  // ---- Phase 1: edge index loads (oldest vmem) ----
  int d[4], s[4];
#pragma unroll
  for (int k = 0; k < 4; ++k) {
    int e = gtid + k * T;
    bool ok = (e < E);
    int ee = ok ? e : 0;
    d[k] = dst[ee];
    s[k] = src[ee];
    if (!ok) d[k] = Nrows;  // dummy node: cursor/edge carved with N+1 rows
  }

  // ---- Phase 2: issue ALL staging loads (both K-tiles) into registers ----
  const int rowbase = blockIdx.x * 64;
  const int r = tid >> 2;
  const bool valid = (rowbase + r) < Nrows;
  float4 w0[8], w1t[8], x0[4], x1t[4];
  {
    int rg = rowbase + r;
    int rs = valid ? rg : (Nrows - 1);
    const float4* xrow = (const float4*)(X + (size_t)rs * 128);
#pragma unroll
    for (int i = 0; i < 8; ++i) {
      int f = tid + i * 256;
      int kk = f >> 5, cc = f & 31;
      w0[i]  = ((const float4*)W1)[(size_t)kk * 32 + cc];
      w1t[i] = ((const float4*)W1)[(size_t)(64 + kk) * 32 + cc];
    }
#pragma unroll
    for (int p = 0; p < 4; ++p) {
      int kf4 = (tid & 3) + p * 4;
      x0[p]  = xrow[kf4];
      x1t[p] = xrow[16 + kf4];
    }
  }
  __builtin_amdgcn_sched_barrier(0);  // pin: atomics must be issued AFTER the staging loads

  // ---- Phase 3: returning atomics (youngest vmem; consumed only in epilogue) ----
  int slot[4];
#pragma unroll
  for (int k = 0; k < 4; ++k) slot[k] = atomicAdd(&cursor[d[k]], 1);
  __builtin_amdgcn_sched_barrier(0);  // pin: nothing from the GEMM hoists above the atomics

  const int cg = tid & 31;
  const int rl = tid >> 5;

  float acc[8][4];
#pragma unroll
  for (int i = 0; i < 8; ++i)
#pragma unroll
    for (int j = 0; j < 4; ++j) acc[i][j] = 0.f;

  // ---- tile 0: write LDS (waits only on tile0 loads: older than atomics) ----
#pragma unroll
  for (int i = 0; i < 8; ++i) {
    int f = tid + i * 256;
    int kk = f >> 5, cc = f & 31;
    *(float4*)&wlds[kk][cc * 4] = w0[i];
  }
#pragma unroll
  for (int p = 0; p < 4; ++p) {
    int kf4 = (tid & 3) + p * 4;
    float4 v = valid ? x0[p] : make_float4(0.f, 0.f, 0.f, 0.f);
    int ke = kf4 * 4;
    xT[ke + 0][r] = v.x;
    xT[ke + 1][r] = v.y;
    xT[ke + 2][r] = v.z;
    xT[ke + 3][r] = v.w;
  }
  lds_fence_barrier();

#pragma unroll 8
  for (int kk = 0; kk < 64; ++kk) {
    float4 xa = *(const float4*)&xT[kk][rl * 8];
    float4 xb = *(const float4*)&xT[kk][rl * 8 + 4];
    float4 wv = *(const float4*)&wlds[kk][cg * 4];
    float xr[8] = {xa.x, xa.y, xa.z, xa.w, xb.x, xb.y, xb.z, xb.w};
    float wc[4] = {wv.x, wv.y, wv.z, wv.w};
#pragma unroll
    for (int i = 0; i < 8; ++i)
#pragma unroll
      for (int j = 0; j < 4; ++j)
        acc[i][j] = fmaf(xr[i], wc[j], acc[i][j]);
  }
  lds_fence_barrier();

  // ---- tile 1: write LDS (waits vmcnt down to the 4 outstanding atomics only) ----
#pragma unroll
  for (int i = 0; i < 8; ++i) {
    int f = tid + i * 256;
    int kk = f >> 5, cc = f & 31;
    *(float4*)&wlds[kk][cc * 4] = w1t[i];
  }
#pragma unroll
  for (int p = 0; p < 4; ++p) {
    int kf4 = (tid & 3) + p * 4;
    float4 v = valid ? x1t[p] : make_float4(0.f, 0.f, 0.f, 0.f);
    int ke = kf4 * 4;
    xT[ke + 0][r] = v.x;
    xT[ke + 1][r] = v.y;
    xT[ke + 2][r] = v.z;
    xT[ke + 3][r] = v.w;
  }
  lds_fence_barrier();

#pragma unroll 8
  for (int kk = 0; kk < 64; ++kk) {
    float4 xa = *(const float4*)&xT[kk][rl * 8];
    float4 xb = *(const float4*)&xT[kk][rl * 8 + 4];
    float4 wv = *(const float4*)&wlds[kk][cg * 4];
    float xr[8] = {xa.x, xa.y, xa.z, xa.w, xb.x, xb.y, xb.z, xb.w};
    float wc[4] = {wv.x, wv.y, wv.z, wv.w};
#pragma unroll
    for (int i = 0; i < 8; ++i)
#pragma unroll
      for (int j = 0; j < 4; ++j)
        acc[i][j] = fmaf(xr[i], wc[j], acc[i][j]);
  }

  // ---- epilogue: C stores, then (finally) consume the atomic results ----
#pragma unroll
  for (int i = 0; i < 8; ++i) {
    int rr = rowbase + rl * 8 + i;
    if (rr >= Nrows) continue;
    uint2 o;
    o.x = pack_bf2(acc[i][0], acc[i][1]);
    o.y = pack_bf2(acc[i][2], acc[i][3]);
    ((uint2*)outG)[(size_t)rr * 32 + cg] = o;
  }
#pragma unroll
  for (int k = 0; k < 4; ++k) {
    if (slot[k] < MAXDEG) edge[(size_t)d[k] * MAXDEG + slot[k]] = (IdxT)s[k];
  }
}

// ---------------- GEMM2: mean/std(fp32) = Xbf @ [W3|W4] + [b3|b4] ----------------
__global__ __launch_bounds__(256) void gemm2_kernel(
    const uint_t* __restrict__ Xbf, const float* __restrict__ W3, const float* __restrict__ W4,
    const float* __restrict__ b3, const float* __restrict__ b4,
    float* __restrict__ outM, float* __restrict__ outS, int Nrows) {
  constexpr int BK = 64;
  __shared__ float wlds[BK][128];
  __shared__ float xT[BK][68];

  const int tid = threadIdx.x;
  const int cg = tid & 31;
  const int rl = tid >> 5;
  const int rowbase = blockIdx.x * 64;

  float acc[8][4];
#pragma unroll
  for (int i = 0; i < 8; ++i)
#pragma unroll
    for (int j = 0; j < 4; ++j) acc[i][j] = 0.f;

  for (int k0 = 0; k0 < 128; k0 += BK) {
    __syncthreads();
#pragma unroll
    for (int i = 0; i < 8; ++i) {
      int f = tid + i * 256;
      int kk = f >> 5, cc = f & 31;
      float4 v = (cc < 16) ? ((const float4*)W3)[(size_t)(k0 + kk) * 16 + cc]
                           : ((const float4*)W4)[(size_t)(k0 + kk) * 16 + (cc - 16)];
      *(float4*)&wlds[kk][cc * 4] = v;
    }
    {
      int r = tid >> 2;
      int rg = rowbase + r;
      int rs = (rg < Nrows) ? rg : (Nrows - 1);
      const uint4* xrow = (const uint4*)(Xbf + (size_t)rs * 64);
      bool valid = (rg < Nrows);
#pragma unroll
      for (int p = 0; p < 2; ++p) {
        int kf8 = (tid & 3) + p * 4;
        uint4 v = xrow[(k0 >> 3) + kf8];
        if (!valid) v = make_uint4(0, 0, 0, 0);
        int ke = kf8 * 8;
        xT[ke + 0][r] = bf_lo(v.x); xT[ke + 1][r] = bf_hi(v.x);
        xT[ke + 2][r] = bf_lo(v.y); xT[ke + 3][r] = bf_hi(v.y);
        xT[ke + 4][r] = bf_lo(v.z); xT[ke + 5][r] = bf_hi(v.z);
        xT[ke + 6][r] = bf_lo(v.w); xT[ke + 7][r] = bf_hi(v.w);
      }
    }
    __syncthreads();
#pragma unroll 8
    for (int kk = 0; kk < BK; ++kk) {
      float4 xa = *(const float4*)&xT[kk][rl * 8];
      float4 xb = *(const float4*)&xT[kk][rl * 8 + 4];
      float4 wv = *(const float4*)&wlds[kk][cg * 4];
      float xr[8] = {xa.x, xa.y, xa.z, xa.w, xb.x, xb.y, xb.z, xb.w};
      float wc[4] = {wv.x, wv.y, wv.z, wv.w};
#pragma unroll
      for (int i = 0; i < 8; ++i)
#pragma unroll
        for (int j = 0; j < 4; ++j)
          acc[i][j] = fmaf(xr[i], wc[j], acc[i][j]);
    }
  }
  float4 bv = (cg < 16) ? ((const float4*)b3)[cg] : ((const float4*)b4)[cg - 16];
#pragma unroll
  for (int i = 0; i < 8; ++i) {
    int r = rowbase + rl * 8 + i;
    if (r >= Nrows) continue;
    float4 o;
    o.x = acc[i][0] + bv.x; o.y = acc[i][1] + bv.y;
    o.z = acc[i][2] + bv.z; o.w = acc[i][3] + bv.w;
    if (cg < 16) ((float4*)outM)[(size_t)r * 16 + cg] = o;
    else         ((float4*)outS)[(size_t)r * 16 + (cg - 16)] = o;
  }
}

// ---------------- gather aggregation (bf16 in/out, fp32 accum) ----------------
template<int EPI, bool SRCDV, typename IdxT>
__global__ __launch_bounds__(256) void aggregate_kernel(
    const uint_t* __restrict__ g, const int* __restrict__ deg,
    const IdxT* __restrict__ edge, const float* __restrict__ b1,
    uint_t* __restrict__ out, int Nn) {
  int wave = threadIdx.x >> 6;
  int lane = threadIdx.x & 63;
  int n = blockIdx.x * 4 + wave;
  if (n >= Nn) return;
  int dn = deg[n];
  int cnt = (dn > MAXDEG) ? MAXDEG : dn;
  float sc = rsqrtf((float)(dn + 1));
  // whole edge row in one coalesced wave-load (64 x 2B = 128B for ushort)
  int myidx = (lane < cnt) ? (int)edge[(size_t)n * MAXDEG + lane] : 0;
  float mydv = 0.f;
  if (SRCDV) mydv = (lane < cnt) ? rsqrtf((float)(deg[myidx] + 1)) : 0.f;
  uint_t su = g[(size_t)n * 64 + lane];
  float selfw = SRCDV ? sc : 1.f;
  float a0x = selfw * bf_lo(su), a0y = selfw * bf_hi(su);
  float a1x = 0.f, a1y = 0.f;
  float a2x = 0.f, a2y = 0.f;
  float a3x = 0.f, a3y = 0.f;
  int i = 0;
  for (; i + 3 < cnt; i += 4) {
    int s0 = __shfl(myidx, i);
    int s1 = __shfl(myidx, i + 1);
    int s2 = __shfl(myidx, i + 2);
    int s3 = __shfl(myidx, i + 3);
    uint_t u0 = g[(size_t)s0 * 64 + lane];
    uint_t u1 = g[(size_t)s1 * 64 + lane];
    uint_t u2 = g[(size_t)s2 * 64 + lane];
    uint_t u3 = g[(size_t)s3 * 64 + lane];
    if (SRCDV) {
      float d0 = __shfl(mydv, i);
      float d1 = __shfl(mydv, i + 1);
      float d2 = __shfl(mydv, i + 2);
      float d3 = __shfl(mydv, i + 3);
      a0x = fmaf(d0, bf_lo(u0), a0x); a0y = fmaf(d0, bf_hi(u0), a0y);
      a1x = fmaf(d1, bf_lo(u1), a1x); a1y = fmaf(d1, bf_hi(u1), a1y);
      a2x = fmaf(d2, bf_lo(u2), a2x); a2y = fmaf(d2, bf_hi(u2), a2y);
      a3x = fmaf(d3, bf_lo(u3), a3x); a3y = fmaf(d3, bf_hi(u3), a3y);
    } else {
      a0x += bf_lo(u0); a0y += bf_hi(u0);
      a1x += bf_lo(u1); a1y += bf_hi(u1);
      a2x += bf_lo(u2); a2y += bf_hi(u2);
      a3x += bf_lo(u3); a3y += bf_hi(u3);
    }
  }
  for (; i < cnt; ++i) {
    int s0 = __shfl(myidx, i);
    uint_t u0 = g[(size_t)s0 * 64 + lane];
    if (SRCDV) {
      float d0 = __shfl(mydv, i);
      a0x = fmaf(d0, bf_lo(u0), a0x); a0y = fmaf(d0, bf_hi(u0), a0y);
    } else {
      a0x += bf_lo(u0); a0y += bf_hi(u0);
    }
  }
  float ox = (a0x + a1x) + (a2x + a3x);
  float oy = (a0y + a1y) + (a2y + a3y);
  if (EPI == 1) {
    float2 b = ((const float2*)b1)[lane];
    ox = fmaxf(fmaf(sc, ox, b.x), 0.f) * sc;
    oy = fmaxf(fmaf(sc, oy, b.y), 0.f) * sc;
  } else {
    ox *= sc; oy *= sc;
  }
  out[(size_t)n * 64 + lane] = pack_bf2(ox, oy);
}

// ---------------- launch ----------------
extern "C" void kernel_launch(void* const* d_in, const int* in_sizes, int n_in,
                              void* d_out, int out_size, void* d_ws, size_t ws_size,
                              hipStream_t stream) {
  const float* x  = (const float*)d_in[0];
  const int*   ei = (const int*)d_in[1];
  const float* W1 = (const float*)d_in[2];
  const float* b1 = (const float*)d_in[3];
  const float* W3 = (const float*)d_in[4];
  const float* b3 = (const float*)d_in[5];
  const float* W4 = (const float*)d_in[6];
  const float* b4 = (const float*)d_in[7];

  const int N = in_sizes[0] / 128;
  const int E = in_sizes[1] / 2;
  const int* src = ei;
  const int* dst = ei + E;

  char* w = (char*)d_ws;
  size_t off = 0;
  auto carve = [&](size_t bytes) { void* p = w + off; off = align256(off + bytes); return p; };
  // +1 dummy node: invalid lanes in the batched scatter bump cursor[N]/edge[N] harmlessly
  int*    cursor = (int*)carve((size_t)(N + 1) * sizeof(int));           // becomes deg after fill
  void*   edge   = carve((size_t)(N + 1) * MAXDEG * sizeof(int));        // sized for int fallback
  uint_t* bufG   = (uint_t*)carve((size_t)N * 64 * sizeof(uint_t));      // [N,128] bf16
  uint_t* bufH   = (uint_t*)carve((size_t)N * 64 * sizeof(uint_t));

  float* out_mean = (float*)d_out;
  float* out_std  = out_mean + (size_t)N * 64;

  hipMemsetAsync(cursor, 0, (size_t)(N + 1) * sizeof(int), stream);

  const int gblocks = (N + 63) / 64;
  const int ablocks = (N + 3) / 4;

  if (N <= 65535) {
    ushort_t* es = (ushort_t*)edge;
    gemm1_fill_kernel<ushort_t><<<gblocks, 256, 0, stream>>>(
        x, W1, bufG, N, src, dst, cursor, es, E);
    aggregate_kernel<1, true,  ushort_t><<<ablocks, 256, 0, stream>>>(bufG, cursor, es, b1, bufH, N);
    aggregate_kernel<2, false, ushort_t><<<ablocks, 256, 0, stream>>>(bufH, cursor, es, nullptr, bufG, N);
  } else {
    int* es = (int*)edge;
    gemm1_fill_kernel<int><<<gblocks, 256, 0, stream>>>(
        x, W1, bufG, N, src, dst, cursor, es, E);
    aggregate_kernel<1, true,  int><<<ablocks, 256, 0, stream>>>(bufG, cursor, es, b1, bufH, N);
    aggregate_kernel<2, false, int><<<ablocks, 256, 0, stream>>>(bufH, cursor, es, nullptr, bufG, N);
  }
  gemm2_kernel<<<gblocks, 256, 0, stream>>>(bufG, W3, W4, b3, b4, out_mean, out_std, N);
}